// Round 4
// baseline (1068.029 us; speedup 1.0000x reference)
//
#include <hip/hip_runtime.h>

#define HH 352
#define WWID 352
#define HW 123904
#define NIMG 2
#define C128 128
#define SCALE_F 0.08838834764831845f
#define RB 154          // region base (row & col)
#define RS 44           // region size
#define RPX 1936        // RS*RS

typedef _Float16 f16x8 __attribute__((ext_vector_type(8)));
typedef float f32x4 __attribute__((ext_vector_type(4)));

__device__ __forceinline__ float silu_f(float v){ return v / (1.0f + __expf(-v)); }

// ============ weight pre-swizzle into A-fragment order for mfma_f32_16x16x32_f16.
__global__ __launch_bounds__(256) void k_wprep(const float* __restrict__ W,
                                               _Float16* __restrict__ Wf, int nct){
  int e = blockIdx.x*256 + threadIdx.x;
  if (e >= nct*256) return;
  int l = e & 63, kc = (e>>6)&3, ct = e>>8;
  const float* src = W + (size_t)(ct*16 + (l&15))*128 + kc*32 + (l>>4)*8;
  f16x8 pk;
#pragma unroll
  for (int j=0;j<8;j++) pk[j] = (_Float16)src[j];
  *(f16x8*)(Wf + (size_t)e*8) = pk;
}

// ============ q conv: 1x1 conv + silu via fp16 MFMA, fused window sums (routing).
template<int COW, bool FUSEW>
__global__ __launch_bounds__(256) void k_conv_mfma(const float* __restrict__ X,
                                                   const _Float16* __restrict__ Wf,
                                                   const float* __restrict__ B,
                                                   float* __restrict__ O,
                                                   float* __restrict__ winsum){
  constexpr int Cout = COW*4;
  constexpr int MT = COW/16;
  __shared__ _Float16 Xs[16*64*8];
  const int t = threadIdx.x;
  const int p0 = blockIdx.x*64;
  const int n = blockIdx.z;
  const int wv = t>>6, l = t&63;
  const float* Xn = X + (size_t)n*C128*HW;
#pragma unroll
  for (int it=0; it<4; it++){
    int kb = it*4 + wv;
    f16x8 pk;
#pragma unroll
    for (int j=0;j<8;j++){
      int ci = kb*8 + j;
      pk[j] = (_Float16)Xn[(size_t)ci*HW + p0 + l];
    }
    *(f16x8*)(&Xs[(kb*64 + l)*8]) = pk;
  }
  __syncthreads();
  const int quad = l>>4, li = l&15;
  f32x4 acc[MT][4];
#pragma unroll
  for (int m=0;m<MT;m++)
#pragma unroll
    for (int nt=0;nt<4;nt++){ acc[m][nt][0]=0.f; acc[m][nt][1]=0.f; acc[m][nt][2]=0.f; acc[m][nt][3]=0.f; }
  const _Float16* Wfw = Wf + (size_t)(wv*MT)*4*64*8;
#pragma unroll
  for (int kc=0; kc<4; kc++){
    f16x8 b[4];
#pragma unroll
    for (int nt=0; nt<4; nt++)
      b[nt] = *(const f16x8*)(&Xs[((kc*4 + quad)*64 + nt*16 + li)*8]);
    f16x8 a[MT];
#pragma unroll
    for (int m=0;m<MT;m++)
      a[m] = *(const f16x8*)(Wfw + (size_t)((m*4 + kc)*64 + l)*8);
#pragma unroll
    for (int m=0;m<MT;m++)
#pragma unroll
      for (int nt=0;nt<4;nt++)
        acc[m][nt] = __builtin_amdgcn_mfma_f32_16x16x32_f16(a[m], b[nt], acc[m][nt], 0, 0, 0);
  }
#pragma unroll
  for (int m=0;m<MT;m++){
    int cob = wv*COW + m*16 + quad*4;
#pragma unroll
    for (int r=0;r<4;r++){
      int co = cob + r;
      float bb = B[co];
      float* Orow = O + ((size_t)n*Cout + co)*HW + p0;
#pragma unroll
      for (int nt=0;nt<4;nt++){
        float y = silu_f(acc[m][nt][r] + bb);
        Orow[nt*16 + li] = y;
        if (FUSEW){
          int pl = p0 + nt*16;
          int row = pl / WWID, col = pl - (pl/WWID)*WWID;
          int p = (row>>5)*11 + (col>>5);
          float ssum = y;
          ssum += __shfl_xor(ssum,1); ssum += __shfl_xor(ssum,2);
          ssum += __shfl_xor(ssum,4); ssum += __shfl_xor(ssum,8);
          if (li == 0)
            atomicAdd(winsum + ((size_t)n*121 + p)*128 + co, ssum);
        }
      }
    }
  }
}

// ============ region GEMM: Y[n][ry][rx][co] = sum_ci kv_w[co][ci]*x[n][ci][RB+ry][RB+rx]
// (no bias, no silu — applied after bilinear combine; exact by linearity).
// grid (31, 1, N), block 256 (4 waves, 64 co each). Y is px-major fp32, 2MB/image.
__global__ __launch_bounds__(256) void k_gemm_region(const float* __restrict__ X,
                                                     const _Float16* __restrict__ Wf,
                                                     float* __restrict__ Y){
  __shared__ _Float16 Xs[16*64*8];
  const int t = threadIdx.x;
  const int tile = blockIdx.x;
  const int n = blockIdx.z;
  const int wv = t>>6, l = t&63;
  const float* Xn = X + (size_t)n*C128*HW;
  const int p = tile*64 + l;
  const bool valid = p < RPX;
  const int ry = p/RS, rx = p - ry*RS;
  const size_t g = (size_t)(RB+ry)*WWID + RB + rx;
#pragma unroll
  for (int it=0; it<4; it++){
    int kb = it*4 + wv;
    f16x8 pk;
#pragma unroll
    for (int j=0;j<8;j++){
      int ci = kb*8 + j;
      pk[j] = (_Float16)(valid ? Xn[(size_t)ci*HW + g] : 0.f);
    }
    *(f16x8*)(&Xs[(kb*64 + l)*8]) = pk;
  }
  __syncthreads();
  const int quad = l>>4, li = l&15;
  f32x4 acc[4][4];
#pragma unroll
  for (int m=0;m<4;m++)
#pragma unroll
    for (int nt=0;nt<4;nt++){ acc[m][nt][0]=0.f; acc[m][nt][1]=0.f; acc[m][nt][2]=0.f; acc[m][nt][3]=0.f; }
  const _Float16* Wfw = Wf + (size_t)(wv*4)*4*64*8;
#pragma unroll
  for (int kc=0; kc<4; kc++){
    f16x8 b[4];
#pragma unroll
    for (int nt=0; nt<4; nt++)
      b[nt] = *(const f16x8*)(&Xs[((kc*4 + quad)*64 + nt*16 + li)*8]);
    f16x8 a[4];
#pragma unroll
    for (int m=0;m<4;m++)
      a[m] = *(const f16x8*)(Wfw + (size_t)((m*4 + kc)*64 + l)*8);
#pragma unroll
    for (int m=0;m<4;m++)
#pragma unroll
      for (int nt=0;nt<4;nt++)
        acc[m][nt] = __builtin_amdgcn_mfma_f32_16x16x32_f16(a[m], b[nt], acc[m][nt], 0, 0, 0);
  }
  // store px-major: Y[(n*RPX + px)*256 + co], lane holds co cob..cob+3 for px nt*16+li
#pragma unroll
  for (int m=0;m<4;m++){
    int cob = wv*64 + m*16 + quad*4;
#pragma unroll
    for (int nt=0;nt<4;nt++){
      int px = tile*64 + nt*16 + li;
      if (px < RPX){
        float4 v = make_float4(acc[m][nt][0], acc[m][nt][1], acc[m][nt][2], acc[m][nt][3]);
        *(float4*)(Y + ((size_t)n*RPX + px)*256 + cob) = v;
      }
    }
  }
}

// ============ kv apply: bilinear-combine Y + bias + silu; store V-half plane-major;
// fused 8x8 pool-max (plain stores) and window K-sums (LDS reduce, plain store).
// grid (121, N), block 512 (8 waves). wave w: rows cr*8..cr*8+8 (cr=w>>1), cols ch*16..+16 (ch=w&1).
// lane l: co = 4l..4l+3.
__global__ __launch_bounds__(512) void k_kv_apply(const float* __restrict__ Y,
                                                  const float* __restrict__ samp,
                                                  const float* __restrict__ kv_b,
                                                  float* __restrict__ vbuf,
                                                  float* __restrict__ kvd,
                                                  float* __restrict__ kwin){
  __shared__ float wsl[8][128];
  const int p = blockIdx.x, n = blockIdx.y;
  const int t = threadIdx.x;
  const int w = t>>6, l = t&63;
  const int cr = w>>1, chh = w&1;
  const int py0 = (p/11)*32, px0 = (p%11)*32;
  const int co4 = l*4;
  const float4 b4 = *(const float4*)(kv_b + co4);
  const float* Yn = Y + (size_t)n*RPX*256;
  const float* sn = samp + (size_t)n*HW*2;
  float* vp_base = vbuf + (size_t)n*C128*HW;
  float4 ws = make_float4(0.f,0.f,0.f,0.f);
  float4 mx[2];
  mx[0] = make_float4(-3e38f,-3e38f,-3e38f,-3e38f);
  mx[1] = make_float4(-3e38f,-3e38f,-3e38f,-3e38f);
  for (int r=0; r<8; r++){
    int gy = py0 + cr*8 + r;
#pragma unroll
    for (int half=0; half<2; half++){
#pragma unroll 4
      for (int c8=0; c8<8; c8++){
        int gx = px0 + chh*16 + half*8 + c8;
        int gp = gy*WWID + gx;
        float2 s2 = *(const float2*)(sn + (size_t)gp*2);
        float x0f = floorf(s2.x), y0f = floorf(s2.y);
        int x0 = (int)x0f - RB, y0 = (int)y0f - RB;
        float fx = s2.x - x0f, fy = s2.y - y0f;
        float w00=(1.f-fx)*(1.f-fy), w01=fx*(1.f-fy), w10=(1.f-fx)*fy, w11=fx*fy;
        const float* Yp = Yn + ((size_t)y0*RS + x0)*256 + co4;
        float4 a  = *(const float4*)(Yp);
        float4 bb = *(const float4*)(Yp + 256);
        float4 c  = *(const float4*)(Yp + RS*256);
        float4 d  = *(const float4*)(Yp + RS*256 + 256);
        float4 o;
        o.x = silu_f(w00*a.x + w01*bb.x + w10*c.x + w11*d.x + b4.x);
        o.y = silu_f(w00*a.y + w01*bb.y + w10*c.y + w11*d.y + b4.y);
        o.z = silu_f(w00*a.z + w01*bb.z + w10*c.z + w11*d.z + b4.z);
        o.w = silu_f(w00*a.w + w01*bb.w + w10*c.w + w11*d.w + b4.w);
        if (co4 >= 128){
          float* vp = vp_base + (size_t)(co4-128)*HW + gp;
          vp[0] = o.x; vp[HW] = o.y; vp[2*HW] = o.z; vp[3*HW] = o.w;
        }
        ws.x += o.x; ws.y += o.y; ws.z += o.z; ws.w += o.w;
        mx[half].x = fmaxf(mx[half].x, o.x);
        mx[half].y = fmaxf(mx[half].y, o.y);
        mx[half].z = fmaxf(mx[half].z, o.z);
        mx[half].w = fmaxf(mx[half].w, o.w);
      }
    }
  }
  // pool cells: cell = cr*4 + chh*2 + half, exclusive owner -> plain store
  size_t cellbase = ((size_t)(n*121 + p))*16 + cr*4 + chh*2;
#pragma unroll
  for (int half=0; half<2; half++)
    *(float4*)(kvd + (cellbase + half)*256 + co4) = mx[half];
  // window K-sums: LDS reduce over 8 waves, plain store
  if (l < 32) *(float4*)(&wsl[w][co4]) = ws;
  __syncthreads();
  if (t < 128){
    float s = 0.f;
#pragma unroll
    for (int w2=0; w2<8; w2++) s += wsl[w2][t];
    kwin[((size_t)n*121 + p)*128 + t] = s;
  }
}

// ============ offset path, channel-split (as round 3).
__global__ __launch_bounds__(256) void k_offset_part(const float* __restrict__ q,
                                                     const float* __restrict__ dww,
                                                     const float* __restrict__ dwb,
                                                     const float* __restrict__ bng,
                                                     const float* __restrict__ bnb,
                                                     const float* __restrict__ pw,
                                                     float* __restrict__ offacc){
  __shared__ float s[3840];
  const int t = threadIdx.x;
  const int X0 = blockIdx.x*32, Y0 = blockIdx.y*16;
  const int n = blockIdx.z >> 2, c0 = (blockIdx.z & 3)*32;
  const int tx = t & 15, ty = t >> 4;
  const int px = X0 + tx*2, py = Y0 + ty;
  const float inv = 1.0f / sqrtf(1.0f + 1e-5f);
  float o0a=0.f,o0b=0.f,o1a=0.f,o1b=0.f;
  float pf[15];
  const float* qn = q + (size_t)n*C128*HW;
  auto issue = [&](int stage){
    int cbase = c0 + stage*4;
#pragma unroll
    for (int i=0;i<15;i++){
      int e = t + i*256;
      int ch = e/960, idx = e - ch*960;
      int rr = idx/40, cc2 = idx - rr*40;
      int gr = Y0 - 4 + rr, gc = X0 - 4 + cc2;
      float v = 0.f;
      if (gr>=0 && gr<HH && gc>=0 && gc<WWID) v = qn[(size_t)(cbase+ch)*HW + gr*WWID + gc];
      pf[i] = v;
    }
  };
  issue(0);
  for (int stage=0; stage<8; stage++){
    __syncthreads();
#pragma unroll
    for (int i=0;i<15;i++) s[t + i*256] = pf[i];
    __syncthreads();
    if (stage < 7) issue(stage+1);
    int cbase = c0 + stage*4;
#pragma unroll
    for (int ch=0; ch<4; ch++){
      int c = cbase + ch;
      const float* wc = dww + c*81;
      const float* sc = s + ch*960;
      float sum0=0.f, sum1=0.f;
#pragma unroll
      for (int r=0;r<9;r++){
        float ld[10];
#pragma unroll
        for (int m2=0;m2<5;m2++){
          float2 v2 = *(const float2*)(sc + (ty+r)*40 + tx*2 + 2*m2);
          ld[2*m2]=v2.x; ld[2*m2+1]=v2.y;
        }
#pragma unroll
        for (int j=0;j<9;j++){
          float wv = wc[r*9+j];
          sum0 += wv*ld[j]; sum1 += wv*ld[j+1];
        }
      }
      float g = inv*bng[c], bet = bnb[c], db = dwb[c];
      float t0 = (sum0+db)*g + bet, t1 = (sum1+db)*g + bet;
      float p0c = pw[c], p1c = pw[C128+c];
      o0a += p0c*t0; o0b += p0c*t1;
      o1a += p1c*t0; o1b += p1c*t1;
    }
  }
  size_t base = ((size_t)n*HW + (size_t)py*WWID + px)*2;
  atomicAdd(offacc + base + 0, o0a);
  atomicAdd(offacc + base + 1, o1a);
  atomicAdd(offacc + base + 2, o0b);
  atomicAdd(offacc + base + 3, o1b);
}

// ============ finalize: offacc -> clamp -> pixel coords (gx, gy).
__global__ __launch_bounds__(256) void k_samp_fin(const float* __restrict__ offacc,
                                                  float* __restrict__ samp){
  int e = blockIdx.x*256 + threadIdx.x;
  int n = e / HW, p = e - n*HW;
  int py = p / WWID, px = p - py*WWID;
  float2 o2 = *(const float2*)(offacc + (size_t)e*2);
  const float k2 = 2.0f/351.0f;
  float ry = (0.5f+(float)py)*k2 - 1.0f, rx = (0.5f+(float)px)*k2 - 1.0f;
  float pyc = fminf(fmaxf(o2.x+ry,-0.12f),0.12f);
  float pxc = fminf(fmaxf(o2.y+rx,-0.12f),0.12f);
  float2 o; o.x = (pxc+1.f)*0.5f*351.f; o.y = (pyc+1.f)*0.5f*351.f;
  *(float2*)(samp + (size_t)e*2) = o;
  (void)n;
}

// ============ routing: logits row + top-4 indices (order-only).
__global__ __launch_bounds__(64) void k_routing(const float* __restrict__ qwin,
                                               const float* __restrict__ kwin,
                                               int* __restrict__ topidx){
  __shared__ float lg[128];
  const int p = blockIdx.x, n = blockIdx.y, l = threadIdx.x;
  const float* qr = qwin + ((size_t)n*121 + p)*128;
  const float* kb = kwin + (size_t)n*121*128;
  float a0 = 0.f, a1 = 0.f;
  const bool has1 = (l + 64) < 121;
  for (int c=0;c<128;c++){
    float qv = qr[c];
    a0 += qv * kb[(size_t)l*128 + c];
    if (has1) a1 += qv * kb[(size_t)(l+64)*128 + c];
  }
  lg[l] = a0;
  lg[64+l] = has1 ? a1 : -3.0e38f;
  __syncthreads();
  if (l == 0){
    for (int j=0;j<4;j++){
      float best = -3.0e38f; int bi = 0;
      for (int i=0;i<121;i++){ if (lg[i] > best){ best = lg[i]; bi = i; } }
      lg[bi] = -3.0e38f;
      topidx[((size_t)n*121 + p)*4 + j] = bi;
    }
  }
}

// ============ windowed attention. grid (121, N, 4 heads), block 256. 2 px/lane.
__global__ __launch_bounds__(256) void k_attention(const float* __restrict__ q,
                                                   const float* __restrict__ kvd,
                                                   const int* __restrict__ topidx,
                                                   float* __restrict__ out){
  __shared__ float ks[64*32];
  __shared__ float vs[64*32];
  __shared__ int tix[4];
  const int p = blockIdx.x, n = blockIdx.y, h = blockIdx.z;
  const int t = threadIdx.x;
  if (t < 4) tix[t] = topidx[((size_t)n*121 + p)*4 + t];
  __syncthreads();
#pragma unroll
  for (int i=0;i<8;i++){
    int e = t + i*256;
    int d = e & 31, k = e >> 5;
    const float* kr = kvd + (((size_t)(n*121) + tix[k>>4])*16 + (k & 15))*256;
    ks[k*32 + d] = kr[h*32 + d];
    vs[k*32 + d] = kr[128 + h*32 + d];
  }
  __syncthreads();
  const int py0 = (p/11)*32, px0 = (p%11)*32;
  const int wv = t >> 6, l = t & 63;
  const float* qh = q + ((size_t)n*C128 + h*32)*HW;
  float* oh = out + ((size_t)n*C128 + h*32)*HW;
  for (int it=0; it<2; it++){
    int pxa = it*512 + wv*128 + l;
    int pxb = pxa + 64;
    size_t offa = (size_t)(py0 + (pxa>>5))*WWID + px0 + (pxa&31);
    size_t offb = (size_t)(py0 + (pxb>>5))*WWID + px0 + (pxb&31);
    float qa[32], qb[32], oa[32], ob[32];
#pragma unroll
    for (int d=0; d<32; d++){
      qa[d] = qh[(size_t)d*HW + offa] * SCALE_F;
      qb[d] = qh[(size_t)d*HW + offb] * SCALE_F;
      oa[d] = 0.f; ob[d] = 0.f;
    }
    float suma = 0.f, sumb = 0.f;
    for (int k=0; k<64; k++){
      const float4* kk4 = (const float4*)(ks + k*32);
      float da = 0.f, db = 0.f;
#pragma unroll
      for (int d4=0; d4<8; d4++){
        float4 kk = kk4[d4];
        da += qa[d4*4+0]*kk.x + qa[d4*4+1]*kk.y + qa[d4*4+2]*kk.z + qa[d4*4+3]*kk.w;
        db += qb[d4*4+0]*kk.x + qb[d4*4+1]*kk.y + qb[d4*4+2]*kk.z + qb[d4*4+3]*kk.w;
      }
      float pa = __expf(da), pb = __expf(db);
      suma += pa; sumb += pb;
      const float4* vv4 = (const float4*)(vs + k*32);
#pragma unroll
      for (int d4=0; d4<8; d4++){
        float4 vvv = vv4[d4];
        oa[d4*4+0] += pa*vvv.x; oa[d4*4+1] += pa*vvv.y; oa[d4*4+2] += pa*vvv.z; oa[d4*4+3] += pa*vvv.w;
        ob[d4*4+0] += pb*vvv.x; ob[d4*4+1] += pb*vvv.y; ob[d4*4+2] += pb*vvv.z; ob[d4*4+3] += pb*vvv.w;
      }
    }
    float ia = 1.0f/suma, ib2 = 1.0f/sumb;
#pragma unroll
    for (int d=0; d<32; d++){
      oh[(size_t)d*HW + offa] = oa[d]*ia;
      oh[(size_t)d*HW + offb] = ob[d]*ib2;
    }
  }
}

// ============ sec: depthwise 3x3 over V (vbuf), added into out. grid (121 tiles, C, N).
__global__ __launch_bounds__(256) void k_sec_add(const float* __restrict__ vbuf,
                                                 const float* __restrict__ secw,
                                                 const float* __restrict__ secb,
                                                 float* __restrict__ out){
  __shared__ float s[34*34];
  const int t = threadIdx.x;
  const int bx = blockIdx.x, c = blockIdx.y, n = blockIdx.z;
  const int X0 = (bx % 11)*32, Y0 = (bx / 11)*32;
  const float* src = vbuf + ((size_t)n*C128 + c)*HW;
  for (int e = t; e < 1156; e += 256){
    int row = e / 34;
    int col = e - row*34;
    int gr = Y0 - 1 + row, gc = X0 - 1 + col;
    s[e] = (gr >= 0 && gr < HH && gc >= 0 && gc < WWID) ? src[gr*WWID + gc] : 0.f;
  }
  __syncthreads();
  const int tx = (t & 7)*4, ty = t >> 3;
  float w[9];
#pragma unroll
  for (int i=0;i<9;i++) w[i] = secw[c*9 + i];
  float4 r = make_float4(0.f,0.f,0.f,0.f);
#pragma unroll
  for (int kr=0; kr<3; kr++){
    const float* row = s + (ty + kr)*34 + tx;
    float a0=row[0],a1=row[1],a2=row[2],a3=row[3],a4=row[4],a5=row[5];
    float w0=w[kr*3], w1=w[kr*3+1], w2=w[kr*3+2];
    r.x += w0*a0 + w1*a1 + w2*a2;
    r.y += w0*a1 + w1*a2 + w2*a3;
    r.z += w0*a2 + w1*a3 + w2*a4;
    r.w += w0*a3 + w1*a4 + w2*a5;
  }
  float bb = secb[c];
  float* op = out + ((size_t)n*C128 + c)*HW + (size_t)(Y0+ty)*WWID + X0 + tx;
  float4 cur = *(float4*)op;
  cur.x += r.x + bb; cur.y += r.y + bb; cur.z += r.z + bb; cur.w += r.w + bb;
  *(float4*)op = cur;
}

extern "C" void kernel_launch(void* const* d_in, const int* in_sizes, int n_in,
                              void* d_out, int out_size, void* d_ws, size_t ws_size,
                              hipStream_t stream) {
  const float* x        = (const float*)d_in[0];
  const float* q_w      = (const float*)d_in[1];
  const float* q_b      = (const float*)d_in[2];
  const float* kv_w     = (const float*)d_in[3];
  const float* kv_b     = (const float*)d_in[4];
  const float* off_dw_w = (const float*)d_in[5];
  const float* off_dw_b = (const float*)d_in[6];
  const float* off_bn_g = (const float*)d_in[7];
  const float* off_bn_b = (const float*)d_in[8];
  const float* off_pw_w = (const float*)d_in[9];
  const float* sec_w    = (const float*)d_in[10];
  const float* sec_b    = (const float*)d_in[11];
  float* outp = (float*)d_out;

  float* qbuf  = (float*)d_ws;                               // N*128*HW
  float* vbuf  = qbuf  + (size_t)NIMG*C128*HW;               // N*128*HW (V only)
  float* samp  = vbuf  + (size_t)NIMG*C128*HW;               // N*HW*2
  float* offacc= samp  + (size_t)NIMG*HW*2;                  // N*HW*2   (zeroed)
  float* qwin  = offacc+ (size_t)NIMG*HW*2;                  // N*121*128 (zeroed)
  float* kwin  = qwin  + (size_t)NIMG*121*128;               // N*121*128 (plain stores)
  float* kvd   = kwin  + (size_t)NIMG*121*128;               // N*121*16*256 (plain stores)
  float* Yreg  = kvd   + (size_t)NIMG*121*16*256;            // N*RPX*256
  int*   tidx  = (int*)(Yreg + (size_t)NIMG*RPX*256);        // N*121*4
  _Float16* wfq  = (_Float16*)(tidx + NIMG*121*4);           // 16384 f16
  _Float16* wfkv = wfq + 16384;                              // 32768 f16

  // zero offacc + qwin (contiguous)
  size_t zbytes = ((size_t)NIMG*HW*2 + (size_t)NIMG*121*128) * 4;
  hipMemsetAsync(offacc, 0, zbytes, stream);

  k_wprep<<<dim3(8), 256, 0, stream>>>(q_w, wfq, 8);
  k_wprep<<<dim3(16), 256, 0, stream>>>(kv_w, wfkv, 16);
  k_conv_mfma<32, true><<<dim3(HW/64, 1, NIMG), 256, 0, stream>>>(x, wfq, q_b, qbuf, qwin);
  k_gemm_region<<<dim3((RPX+63)/64, 1, NIMG), 256, 0, stream>>>(x, wfkv, Yreg);
  k_offset_part<<<dim3(11, 22, NIMG*4), 256, 0, stream>>>(
      qbuf, off_dw_w, off_dw_b, off_bn_g, off_bn_b, off_pw_w, offacc);
  k_samp_fin<<<dim3(NIMG*HW/256), 256, 0, stream>>>(offacc, samp);
  k_kv_apply<<<dim3(121, NIMG), 512, 0, stream>>>(Yreg, samp, kv_b, vbuf, kvd, kwin);
  k_routing<<<dim3(121, NIMG), 64, 0, stream>>>(qwin, kwin, tidx);
  k_attention<<<dim3(121, NIMG, 4), 256, 0, stream>>>(qbuf, kvd, tidx, outp);
  k_sec_add<<<dim3(121, 128, NIMG), 256, 0, stream>>>(vbuf, sec_w, sec_b, outp);
}